// Round 5
// baseline (253.485 us; speedup 1.0000x reference)
//
#include <hip/hip_runtime.h>
#include <math.h>

#define NB 256     // batch
#define IC 1152    // input capsules
#define OC 10      // output capsules
#define OU 16      // output units
#define IK 8       // input units
#define KTOT (IC * IK)        // 9216
#define NTOT (OC * OU)        // 160
#define S_KS 16               // fallback s-pass K-splits
#define BLP 584               // fallback B-tile pitch
#define GRID 512              // 2 blocks/CU guaranteed by launch_bounds(256,2)
#define SPB 160               // spass blocks (16 m-tiles x 10 nt)

typedef __attribute__((ext_vector_type(8))) short short8;
typedef __attribute__((ext_vector_type(4))) float f32x4;
typedef unsigned int u32;
typedef unsigned long long u64;

static __device__ __forceinline__ unsigned short f2bf(float f) {
    unsigned u = __float_as_uint(f);
    unsigned r = (u + 0x7FFF + ((u >> 16) & 1)) >> 16;   // RNE
    return (unsigned short)r;
}

// --- device-coherent (sc1) accessors: store lands at L3; load bypasses L1/L2.
static __device__ __forceinline__ void st_u32(u32* p, u32 v) {
    __hip_atomic_store(p, v, __ATOMIC_RELAXED, __HIP_MEMORY_SCOPE_AGENT);
}
static __device__ __forceinline__ u32 ld_u32(const u32* p) {
    return __hip_atomic_load(p, __ATOMIC_RELAXED, __HIP_MEMORY_SCOPE_AGENT);
}
static __device__ __forceinline__ void st_u64(u64* p, u64 v) {
    __hip_atomic_store(p, v, __ATOMIC_RELAXED, __HIP_MEMORY_SCOPE_AGENT);
}
static __device__ __forceinline__ u64 ld_u64(const u64* p) {
    return __hip_atomic_load(p, __ATOMIC_RELAXED, __HIP_MEMORY_SCOPE_AGENT);
}
static __device__ __forceinline__ void stf(float* p, float v) { st_u32((u32*)p, __float_as_uint(v)); }
static __device__ __forceinline__ float ldf(const float* p)   { return __uint_as_float(ld_u32((const u32*)p)); }

// load 8 coherent f32 and convert to bf16x8 (bit-exact vs bf16 vT path)
static __device__ __forceinline__ short8 ld_v8(const float* p) {
    short8 r;
#pragma unroll
    for (int j = 0; j < 4; ++j) {
        union { u64 q; float f[2]; } U;
        U.q = ld_u64((const u64*)(p + j * 2));
        r[j * 2]     = (short)f2bf(U.f[0]);
        r[j * 2 + 1] = (short)f2bf(U.f[1]);
    }
    return r;
}

// RMW-free flag barrier. R4 post-mortem: same-line sc1 fetch_add x64
// serializes at the coherent point (~13us/barrier). Here: arrival is ONE
// independent sc1 store per block (512 distinct words, no serialization);
// wait = all 256 threads poll the 2KB flag array (one coalesced u64 sc1
// load each) + __syncthreads_and. __syncthreads before the flag store
// drains vmcnt(0) -> all sc1 data stores are at L3 before the flag lands.
static __device__ __forceinline__ void gbar(u32* flags, unsigned ph) {
    __syncthreads();
    if (threadIdx.x == 0) st_u32(&flags[blockIdx.x], ph);
    const u64* f64 = (const u64*)flags;
    for (;;) {
        u64 pair = ld_u64(&f64[threadIdx.x]);         // flags[2*tid], flags[2*tid+1]
        bool ok = ((u32)pair >= ph) && ((u32)(pair >> 32) >= ph);
        if (__syncthreads_and(ok)) break;
        __builtin_amdgcn_s_sleep(1);
    }
}

// ---- full-K s-pass + in-block squash. Block = (mt 16-batch rows, nt).
// 4 waves split K=9216 (288 i each, 72 MFMA); B-frags built in registers
// from c*W (no LDS staging, no part[], no reduce phase).
// mode 0: t=0 (c==0.1 exactly, A from f32 inp)  1: mid  2: final->vout
static __device__ __forceinline__ void spass_block(
    int blk, int tid, int mode,
    const float* __restrict__ inp, const unsigned short* __restrict__ inpb,
    const float* __restrict__ W, const float* __restrict__ blog,
    float* __restrict__ vTf, float* __restrict__ vout,
    float* c_loc, float (*sred)[16][17])
{
    const int nt   = blk % 10;
    const int mt   = blk / 10;
    const int lane = tid & 63;
    const int wid  = tid >> 6;
    const int q    = lane >> 4;
    const int l15  = lane & 15;

    if (mode == 0) {
        for (int ii = tid; ii < IC; ii += 256) c_loc[ii] = 0.1f;  // softmax(0) == 1/10
    } else {
        for (int ii = tid; ii < IC; ii += 256) {
            const float* br = &blog[(size_t)ii * OC];
            float x[OC], m = -1e30f;
#pragma unroll
            for (int o = 0; o < OC; ++o) { x[o] = ldf(&br[o]); m = fmaxf(m, x[o]); }
            float ssum = 0.f;
#pragma unroll
            for (int o = 0; o < OC; ++o) ssum += expf(x[o] - m);
            c_loc[ii] = expf(x[nt] - m) / ssum;
        }
    }
    __syncthreads();

    const int i_base = wid * 288;           // wave K-chunk: i in [i_base, i_base+288)
    f32x4 acc = {0.f, 0.f, 0.f, 0.f};

    if (mode == 0) {
        const float* af = inp + (size_t)(mt * 16 + l15) * KTOT + ((size_t)i_base + q) * 8;
#pragma unroll 4
        for (int kk = 0; kk < 72; ++kk) {
            float4 a0 = *(const float4*)(af + kk * 32);
            float4 a1 = *(const float4*)(af + kk * 32 + 4);
            int i = i_base + kk * 4 + q;
            const float* wr = W + (((size_t)i * OC + nt) * OU + l15) * IK;
            float4 w0 = *(const float4*)wr;
            float4 w1 = *(const float4*)(wr + 4);
            float cc = c_loc[i];
            union { short8 v; unsigned short us[8]; } A, B;
            A.us[0] = f2bf(a0.x); A.us[1] = f2bf(a0.y); A.us[2] = f2bf(a0.z); A.us[3] = f2bf(a0.w);
            A.us[4] = f2bf(a1.x); A.us[5] = f2bf(a1.y); A.us[6] = f2bf(a1.z); A.us[7] = f2bf(a1.w);
            B.us[0] = f2bf(cc * w0.x); B.us[1] = f2bf(cc * w0.y);
            B.us[2] = f2bf(cc * w0.z); B.us[3] = f2bf(cc * w0.w);
            B.us[4] = f2bf(cc * w1.x); B.us[5] = f2bf(cc * w1.y);
            B.us[6] = f2bf(cc * w1.z); B.us[7] = f2bf(cc * w1.w);
            acc = __builtin_amdgcn_mfma_f32_16x16x32_bf16(A.v, B.v, acc, 0, 0, 0);
        }
    } else {
        const unsigned short* ap = inpb + (size_t)(mt * 16 + l15) * KTOT + ((size_t)i_base + q) * 8;
#pragma unroll 4
        for (int kk = 0; kk < 72; ++kk) {
            short8 av = *(const short8*)(ap + kk * 32);
            int i = i_base + kk * 4 + q;
            const float* wr = W + (((size_t)i * OC + nt) * OU + l15) * IK;
            float4 w0 = *(const float4*)wr;
            float4 w1 = *(const float4*)(wr + 4);
            float cc = c_loc[i];
            union { short8 v; unsigned short us[8]; } B;
            B.us[0] = f2bf(cc * w0.x); B.us[1] = f2bf(cc * w0.y);
            B.us[2] = f2bf(cc * w0.z); B.us[3] = f2bf(cc * w0.w);
            B.us[4] = f2bf(cc * w1.x); B.us[5] = f2bf(cc * w1.y);
            B.us[6] = f2bf(cc * w1.z); B.us[7] = f2bf(cc * w1.w);
            acc = __builtin_amdgcn_mfma_f32_16x16x32_bf16(av, B.v, acc, 0, 0, 0);
        }
    }

    // cross-wave K-reduction + squash, all in-block
#pragma unroll
    for (int r = 0; r < 4; ++r) sred[wid][q * 4 + r][l15] = acc[r];  // C: row=q*4+r, col=l15
    __syncthreads();

    const int b = tid >> 4, u = tid & 15;
    float s = (sred[0][b][u] + sred[1][b][u]) + (sred[2][b][u] + sred[3][b][u]);
    float sq = s * s;
    sq += __shfl_xor(sq, 1);   // sum over u within aligned 16-lane groups
    sq += __shfl_xor(sq, 2);
    sq += __shfl_xor(sq, 4);
    sq += __shfl_xor(sq, 8);
    float vv = s * (sq / ((1.f + sq) * sqrtf(sq + 1e-9f)));
    if (mode == 2)
        vout[(size_t)(mt * 16 + b) * NTOT + nt * 16 + u] = vv;
    else
        stf(&vTf[(size_t)(nt * 16 + u) * 256 + mt * 16 + b], vv);
}

// ---- delta: 2880 tiles grid-strided over 2048 waves; first=store (blog
// needs no init since softmax(0)=0.1 handles t=0 and delta0 overwrites).
static __device__ __forceinline__ void delta_all(
    int blk, int tid,
    const unsigned short* __restrict__ inpT, const float* __restrict__ vTf,
    const float* __restrict__ W, float* __restrict__ blog, bool first)
{
    const int lane = tid & 63;
    const int wid  = tid >> 6;
    for (int g = blk * 4 + wid; g < 2880; g += GRID * 4) {
        const int mt   = g % 576;
        const int ntp  = g / 576;           // 0..4 -> nt = ntp*2, ntp*2+1
        const int l15  = lane & 15;
        const int quad = lane >> 4;
        const int koff = quad * 8;
        const int nt0  = ntp * 2;

        const unsigned short* ap = inpT + (size_t)(mt * 16 + l15) * 256 + koff;
        const float* bp0 = vTf + (size_t)(nt0 * 16 + l15) * 256 + koff;
        const float* bp1 = bp0 + 16 * 256;

        f32x4 acc0 = {0.f, 0.f, 0.f, 0.f};
        f32x4 acc1 = {0.f, 0.f, 0.f, 0.f};
#pragma unroll
        for (int kk = 0; kk < 8; ++kk) {
            short8 av = *(const short8*)(ap + kk * 32);   // plain: immutable
            short8 b0 = ld_v8(bp0 + kk * 32);             // sc1 + cvt (bit-exact)
            short8 b1 = ld_v8(bp1 + kk * 32);
            acc0 = __builtin_amdgcn_mfma_f32_16x16x32_bf16(av, b0, acc0, 0, 0, 0);
            acc1 = __builtin_amdgcn_mfma_f32_16x16x32_bf16(av, b1, acc1, 0, 0, 0);
        }

        // lane holds G[m=quad*4+r][n=l15]; m -> i_loc = quad>>1, k=(quad&1)*4+r
        const int i = mt * 2 + (quad >> 1);
        const float* wr0 = W + (((size_t)i * OC + nt0) * OU + l15) * IK + (quad & 1) * 4;
        float4 wf0 = *(const float4*)wr0;
        float4 wf1 = *(const float4*)(wr0 + OU * IK);     // nt0+1 adjacent in W
        float w0 = wf0.x * acc0[0] + wf0.y * acc0[1] + wf0.z * acc0[2] + wf0.w * acc0[3];
        float w1 = wf1.x * acc1[0] + wf1.y * acc1[1] + wf1.z * acc1[2] + wf1.w * acc1[3];

#pragma unroll
        for (int d = 0; d < 5; ++d) {
            int m = (d == 0) ? 16 : (1 << (d - 1));       // 16, 1, 2, 4, 8
            w0 += __shfl_xor(w0, m);
            w1 += __shfl_xor(w1, m);
        }

        if ((lane & 31) == 0) {                           // one writer per (i,o)
            float* b0p = &blog[(size_t)i * OC + nt0];
            if (first) {
                stf(b0p,     w0 * (1.0f / NB));
                stf(b0p + 1, w1 * (1.0f / NB));
            } else {
                stf(b0p,     ldf(b0p)     + w0 * (1.0f / NB));
                stf(b0p + 1, ldf(b0p + 1) + w1 * (1.0f / NB));
            }
        }
    }
}

// ===================== fused cooperative kernel =====================
// [spass0 || prep] -> bar -> delta0 -> bar -> spass1 -> bar -> delta1
// -> bar -> spass2.  4 barriers (was 8); no part[]/reduce phase.
__global__ __launch_bounds__(256, 2) void fused_kernel(
    const float* __restrict__ inp,        // [256][1152][8]
    const float* __restrict__ W,          // [1152][10][16][8]
    float* __restrict__ blog,             // [1152][10]       (sc1)
    unsigned short* __restrict__ inpb,    // [256][9216] bf16 (immutable after bar 1... written in phase A)
    unsigned short* __restrict__ inpT,    // [9216][256] bf16
    float* __restrict__ vTf,              // [160][256] f32   (sc1)
    float* __restrict__ vout,             // [256][10][16]
    u32* flags)                           // [512] barrier flags (memset 0)
{
    const int blk = blockIdx.x;
    const int tid = threadIdx.x;

    __shared__ unsigned short sh[64][65];      // prep transpose buffer (8.3 KB)
    __shared__ float c_loc[IC];                // 4.6 KB
    __shared__ float sred[4][16][17];          // 4.4 KB

    // ---------------- phase A: spass(t=0) on blocks<160  ||  prep on the rest
    if (blk < SPB) {
        spass_block(blk, tid, 0, inp, inpb, W, blog, vTf, vout, c_loc, sred);
    } else {
        for (int vb = blk - SPB; vb < 576; vb += (GRID - SPB)) {
            __syncthreads();                   // protect sh reuse across vb iters
            const int kt = vb % 144;
            const int bt = vb / 144;
#pragma unroll
            for (int j = 0; j < 4; ++j) {
                int q     = j * 256 + tid;
                int b_loc = q >> 4;
                int kq    = (q & 15) * 4;
                float4 g = *(const float4*)&inp[(size_t)(bt * 64 + b_loc) * KTOT + kt * 64 + kq];
                unsigned short h0 = f2bf(g.x), h1 = f2bf(g.y), h2 = f2bf(g.z), h3 = f2bf(g.w);
                sh[kq][b_loc] = h0; sh[kq + 1][b_loc] = h1;
                sh[kq + 2][b_loc] = h2; sh[kq + 3][b_loc] = h3;
                u64 pk = (u64)h0 | ((u64)h1 << 16) | ((u64)h2 << 32) | ((u64)h3 << 48);
                st_u64((u64*)&inpb[(size_t)(bt * 64 + b_loc) * KTOT + kt * 64 + kq], pk);
            }
            __syncthreads();
#pragma unroll
            for (int j = 0; j < 4; ++j) {
                int q     = j * 256 + tid;
                int k_loc = q >> 4;
                int b4    = (q & 15) * 4;
                u64 pk = (u64)sh[k_loc][b4] | ((u64)sh[k_loc][b4 + 1] << 16)
                       | ((u64)sh[k_loc][b4 + 2] << 32) | ((u64)sh[k_loc][b4 + 3] << 48);
                st_u64((u64*)&inpT[(size_t)(kt * 64 + k_loc) * 256 + bt * 64 + b4], pk);
            }
        }
    }
    gbar(flags, 1);

    delta_all(blk, tid, inpT, vTf, W, blog, true);    // t=0: store (no blog init)
    gbar(flags, 2);

    if (blk < SPB)
        spass_block(blk, tid, 1, inp, inpb, W, blog, vTf, vout, c_loc, sred);
    gbar(flags, 3);

    delta_all(blk, tid, inpT, vTf, W, blog, false);   // t=1: accumulate
    gbar(flags, 4);

    if (blk < SPB)
        spass_block(blk, tid, 2, inp, inpb, W, blog, vTf, vout, c_loc, sred);
}

// ===================== fallback: proven multi-kernel path (127.9us) =====

__global__ __launch_bounds__(256) void prep_kernel(
    const float* __restrict__ inp,
    float* __restrict__ blog,
    unsigned short* __restrict__ inpb,
    unsigned short* __restrict__ inpT)
{
    const int kt  = blockIdx.x;
    const int bt  = blockIdx.y;
    const int tid = threadIdx.x;
    {
        int bid = blockIdx.y * 144 + blockIdx.x;
        if (bid < 45) blog[bid * 256 + tid] = 0.f;
    }
    __shared__ unsigned short sh[64][65];
#pragma unroll
    for (int j = 0; j < 4; ++j) {
        int q = j * 256 + tid;
        int b_loc = q >> 4;
        int kq = (q & 15) * 4;
        float4 g = *(const float4*)&inp[(size_t)(bt * 64 + b_loc) * KTOT + kt * 64 + kq];
        unsigned short h0 = f2bf(g.x), h1 = f2bf(g.y), h2 = f2bf(g.z), h3 = f2bf(g.w);
        sh[kq][b_loc] = h0; sh[kq + 1][b_loc] = h1;
        sh[kq + 2][b_loc] = h2; sh[kq + 3][b_loc] = h3;
        short4 pk = { (short)h0, (short)h1, (short)h2, (short)h3 };
        *(short4*)&inpb[(size_t)(bt * 64 + b_loc) * KTOT + kt * 64 + kq] = pk;
    }
    __syncthreads();
#pragma unroll
    for (int j = 0; j < 4; ++j) {
        int q = j * 256 + tid;
        int k_loc = q >> 4;
        int b4 = (q & 15) * 4;
        short4 pk = { (short)sh[k_loc][b4],     (short)sh[k_loc][b4 + 1],
                      (short)sh[k_loc][b4 + 2], (short)sh[k_loc][b4 + 3] };
        *(short4*)&inpT[(size_t)(kt * 64 + k_loc) * 256 + bt * 64 + b4] = pk;
    }
}

__global__ __launch_bounds__(256) void spass_kernel(
    const unsigned short* __restrict__ inpb,
    const float* __restrict__ W,
    const float* __restrict__ blog,
    float* __restrict__ part)
{
    const int bid  = blockIdx.x;
    const int nt   = bid % 10;
    const int ks   = (bid / 10) % 16;
    const int mtg  = bid / 160;
    const int tid  = threadIdx.x;
    const int w    = tid >> 6;
    const int lane = tid & 63;
    const int l15  = lane & 15;
    const int koff = (lane >> 4) * 8;
    const int k0   = ks * 576;
    const int i0   = ks * 72;
    const int mt   = mtg * 4 + w;

    __shared__ unsigned short Bl[16 * BLP];
    __shared__ float c_loc[72];

    if (tid < 72) {
        const float* br = &blog[(size_t)(i0 + tid) * OC];
        float x[OC], m = -1e30f;
#pragma unroll
        for (int o = 0; o < OC; ++o) { x[o] = br[o]; m = fmaxf(m, x[o]); }
        float ssum = 0.f;
#pragma unroll
        for (int o = 0; o < OC; ++o) ssum += expf(x[o] - m);
        c_loc[tid] = expf(x[nt] - m) / ssum;
    }
    __syncthreads();
#pragma unroll
    for (int jj = 0; jj < 5; ++jj) {
        int q = jj * 256 + tid;
        if (q < 1152) {
            int i_loc = q >> 4, u = q & 15;
            const float* wr = W + (((size_t)(i0 + i_loc) * OC + nt) * OU + u) * IK;
            float4 a = *(const float4*)wr;
            float4 b = *(const float4*)(wr + 4);
            float cc = c_loc[i_loc];
            union { short8 v; unsigned short us[8]; } pk;
            pk.us[0] = f2bf(cc * a.x); pk.us[1] = f2bf(cc * a.y);
            pk.us[2] = f2bf(cc * a.z); pk.us[3] = f2bf(cc * a.w);
            pk.us[4] = f2bf(cc * b.x); pk.us[5] = f2bf(cc * b.y);
            pk.us[6] = f2bf(cc * b.z); pk.us[7] = f2bf(cc * b.w);
            *(short8*)&Bl[u * BLP + i_loc * 8] = pk.v;
        }
    }
    __syncthreads();

    const unsigned short* ap  = inpb + (size_t)(mt * 16 + l15) * KTOT + k0 + koff;
    const unsigned short* bls = &Bl[l15 * BLP + koff];
    f32x4 acc = {0.f, 0.f, 0.f, 0.f};
#pragma unroll
    for (int kk = 0; kk < 18; ++kk) {
        short8 av = *(const short8*)(ap + kk * 32);
        short8 bv = *(const short8*)(bls + kk * 32);
        acc = __builtin_amdgcn_mfma_f32_16x16x32_bf16(av, bv, acc, 0, 0, 0);
    }
    float* pp = part + ((size_t)ks * NB + mt * 16 + (lane >> 4) * 4) * NTOT + nt * 16 + l15;
#pragma unroll
    for (int r = 0; r < 4; ++r)
        pp[(size_t)r * NTOT] = acc[r];
}

__global__ __launch_bounds__(256) void reduce_squash_kernel(
    const float* __restrict__ part, float* __restrict__ vout,
    unsigned short* __restrict__ vT)
{
    const int tid = threadIdx.x;
    const int el  = tid & 31;
    const int kl  = tid >> 5;
    const int e   = blockIdx.x * 32 + el;

    float a = part[(size_t)(kl * 2) * (NB * NTOT) + e]
            + part[(size_t)(kl * 2 + 1) * (NB * NTOT) + e];

    __shared__ float red[8][36];
    red[kl][el] = a;
    __syncthreads();

    if (tid < 32) {
        float s = ((red[0][el] + red[1][el]) + (red[2][el] + red[3][el]))
                + ((red[4][el] + red[5][el]) + (red[6][el] + red[7][el]));
        float sq = s * s;
        sq += __shfl_xor(sq, 1);
        sq += __shfl_xor(sq, 2);
        sq += __shfl_xor(sq, 4);
        sq += __shfl_xor(sq, 8);
        float vv = s * (sq / ((1.f + sq) * sqrtf(sq + 1e-9f)));
        vout[e] = vv;
        int n = e % NTOT, b = e / NTOT;
        vT[(size_t)n * 256 + b] = f2bf(vv);
    }
}

__global__ __launch_bounds__(256) void delta_kernel(
    const unsigned short* __restrict__ inpT,
    const unsigned short* __restrict__ vT,
    const float* __restrict__ W,
    float* __restrict__ blog)
{
    const int g    = blockIdx.x * 4 + (threadIdx.x >> 6);
    const int lane = threadIdx.x & 63;
    const int mt   = g % 576;
    const int ntp  = g / 576;
    const int l15  = lane & 15;
    const int quad = lane >> 4;
    const int koff = quad * 8;
    const int nt0  = ntp * 2;

    const unsigned short* ap  = inpT + (size_t)(mt * 16 + l15) * 256 + koff;
    const unsigned short* bp0 = vT   + (size_t)(nt0 * 16 + l15) * 256 + koff;
    const unsigned short* bp1 = bp0 + 16 * 256;

    f32x4 acc0 = {0.f, 0.f, 0.f, 0.f};
    f32x4 acc1 = {0.f, 0.f, 0.f, 0.f};
#pragma unroll
    for (int kk = 0; kk < 8; ++kk) {
        short8 av = *(const short8*)(ap  + kk * 32);
        short8 b0 = *(const short8*)(bp0 + kk * 32);
        short8 b1 = *(const short8*)(bp1 + kk * 32);
        acc0 = __builtin_amdgcn_mfma_f32_16x16x32_bf16(av, b0, acc0, 0, 0, 0);
        acc1 = __builtin_amdgcn_mfma_f32_16x16x32_bf16(av, b1, acc1, 0, 0, 0);
    }
    const int i = mt * 2 + (quad >> 1);
    const float* wr0 = W + (((size_t)i * OC + nt0) * OU + l15) * IK + (quad & 1) * 4;
    float4 wf0 = *(const float4*)wr0;
    float4 wf1 = *(const float4*)(wr0 + OU * IK);
    float w0 = wf0.x * acc0[0] + wf0.y * acc0[1] + wf0.z * acc0[2] + wf0.w * acc0[3];
    float w1 = wf1.x * acc1[0] + wf1.y * acc1[1] + wf1.z * acc1[2] + wf1.w * acc1[3];
#pragma unroll
    for (int d = 0; d < 5; ++d) {
        int m = (d == 0) ? 16 : (1 << (d - 1));
        w0 += __shfl_xor(w0, m);
        w1 += __shfl_xor(w1, m);
    }
    if ((lane & 31) == 0) {
        blog[(size_t)i * OC + nt0]     += w0 * (1.0f / NB);
        blog[(size_t)i * OC + nt0 + 1] += w1 * (1.0f / NB);
    }
}

extern "C" void kernel_launch(void* const* d_in, const int* in_sizes, int n_in,
                              void* d_out, int out_size, void* d_ws, size_t ws_size,
                              hipStream_t stream) {
    const float* inp = (const float*)d_in[0];   // [256][1152][8]
    const float* W   = (const float*)d_in[1];   // [1152][10][16][8]
    float* vout = (float*)d_out;                // [256][10][16]

    float* blog = (float*)d_ws;                              // 11,520 f
    float* part = blog + IC * OC;                            // 655,360 f (fallback only)
    unsigned short* inpb = (unsigned short*)(part + (size_t)S_KS * NB * NTOT);
    unsigned short* inpT = inpb + (size_t)NB * KTOT;         // 2,359,296 u16
    float* vTf = (float*)(inpT + (size_t)KTOT * 256);        // 40,960 f32
    size_t bar_off = (((size_t)(vTf + NTOT * 256) - (size_t)d_ws) + 127) & ~(size_t)127;
    u32* flags = (u32*)((char*)d_ws + bar_off);              // 512 u32

    hipMemsetAsync(flags, 0, 2048, stream);     // reset barrier flags each replay

    void* args[] = { (void*)&inp, (void*)&W, (void*)&blog,
                     (void*)&inpb, (void*)&inpT, (void*)&vTf, (void*)&vout,
                     (void*)&flags };
    hipError_t err = hipLaunchCooperativeKernel(fused_kernel, dim3(GRID), dim3(256),
                                                args, 0u, stream);
    if (err != hipSuccess) {
        // graceful fallback: the verified multi-kernel path
        unsigned short* vT = (unsigned short*)vTf;   // reuse region as bf16 vT
        prep_kernel<<<dim3(144, 4), dim3(256), 0, stream>>>(inp, blog, inpb, inpT);
        for (int t = 0; t < 3; ++t) {
            spass_kernel<<<dim3(640), dim3(256), 0, stream>>>(inpb, W, blog, part);
            reduce_squash_kernel<<<dim3(NB * NTOT / 32), dim3(256), 0, stream>>>(part, vout, vT);
            if (t < 2)
                delta_kernel<<<dim3(720), dim3(256), 0, stream>>>(inpT, vT, W, blog);
        }
    }
}

// Round 6
// 227.865 us; speedup vs baseline: 1.1124x; 1.1124x over previous
//
#include <hip/hip_runtime.h>
#include <math.h>

#define NB 256     // batch
#define IC 1152    // input capsules
#define OC 10      // output capsules
#define OU 16      // output units
#define IK 8       // input units
#define KTOT (IC * IK)        // 9216
#define NTOT (OC * OU)        // 160
#define S_KS 16               // s-pass K-splits (576 k = 18 MFMA each)
#define BLP 584               // B-tile row pitch in shorts (576 + 8 pad)
#define GRID 512              // 2 blocks/CU guaranteed by launch_bounds(256,2)
#define RELW 544              // release word index (own 128B line: 544*4 = 2176)

typedef __attribute__((ext_vector_type(8))) short short8;
typedef __attribute__((ext_vector_type(4))) float f32x4;
typedef unsigned int u32;
typedef unsigned long long u64;

static __device__ __forceinline__ unsigned short f2bf(float f) {
    unsigned u = __float_as_uint(f);
    unsigned r = (u + 0x7FFF + ((u >> 16) & 1)) >> 16;   // RNE
    return (unsigned short)r;
}

// --- device-coherent (sc1) accessors: store lands at L3; load bypasses L1/L2.
static __device__ __forceinline__ void st_u32(u32* p, u32 v) {
    __hip_atomic_store(p, v, __ATOMIC_RELAXED, __HIP_MEMORY_SCOPE_AGENT);
}
static __device__ __forceinline__ u32 ld_u32(const u32* p) {
    return __hip_atomic_load(p, __ATOMIC_RELAXED, __HIP_MEMORY_SCOPE_AGENT);
}
static __device__ __forceinline__ void st_u64(u64* p, u64 v) {
    __hip_atomic_store(p, v, __ATOMIC_RELAXED, __HIP_MEMORY_SCOPE_AGENT);
}
static __device__ __forceinline__ u64 ld_u64(const u64* p) {
    return __hip_atomic_load(p, __ATOMIC_RELAXED, __HIP_MEMORY_SCOPE_AGENT);
}
static __device__ __forceinline__ void stf(float* p, float v) { st_u32((u32*)p, __float_as_uint(v)); }
static __device__ __forceinline__ float ldf(const float* p)   { return __uint_as_float(ld_u32((const u32*)p)); }

// load 8 coherent f32 and convert to bf16x8 (bit-exact vs bf16 vT path)
static __device__ __forceinline__ short8 ld_v8(const float* p) {
    short8 r;
#pragma unroll
    for (int j = 0; j < 4; ++j) {
        union { u64 q; float f[2]; } U;
        U.q = ld_u64((const u64*)(p + j * 2));
        r[j * 2]     = (short)f2bf(U.f[0]);
        r[j * 2 + 1] = (short)f2bf(U.f[1]);
    }
    return r;
}

// Scan+release grid barrier.
// R4 post-mortem: 64 serialized same-line sc1 RMWs per sub-counter ~= 10us.
// R5 post-mortem: all-256-thread polling by waiting blocks = multi-TB/s of
// L3 poll traffic that throttles the active blocks.
// This design: arrival = ONE independent flag store per block (no RMW, no
// contention). Detection = block 0 ONLY scans all 512 flags (2KB/round).
// Release = one word; waiting blocks poll it with ONE thread each
// (511 x 64B per ~250ns ~= 130 GB/s, harmless). __syncthreads before the
// flag store drains vmcnt(0) -> all sc1 data stores at L3 before flag lands.
static __device__ __forceinline__ void gbar(u32* flags, unsigned ph) {
    __syncthreads();
    if (threadIdx.x == 0) st_u32(&flags[blockIdx.x], ph);
    if (blockIdx.x == 0) {
        const u64* f64 = (const u64*)flags;
        for (;;) {
            u64 pair = ld_u64(&f64[threadIdx.x]);     // 256 threads x 2 flags
            bool ok = ((u32)pair >= ph) && ((u32)(pair >> 32) >= ph);
            if (__syncthreads_and(ok)) break;
            __builtin_amdgcn_s_sleep(1);
        }
        if (threadIdx.x == 0) st_u32(&flags[RELW], ph);
        __syncthreads();
    } else {
        if (threadIdx.x == 0)
            while (ld_u32(&flags[RELW]) < ph) __builtin_amdgcn_s_sleep(2);
        __syncthreads();
    }
}

// ===================== fused cooperative kernel =====================
// R4 phase bodies VERBATIM (proven 146us): prep -> [spass -> reduce+squash
// -> delta]x3, 8 barriers. Only the barrier primitive changed this round.
__global__ __launch_bounds__(256, 2) void fused_kernel(
    const float* __restrict__ inp,        // [256][1152][8]
    const float* __restrict__ W,          // [1152][10][16][8]
    float* __restrict__ blog,             // [1152][10]          (sc1)
    float* __restrict__ part,             // [16][256][160]      (sc1)
    unsigned short* __restrict__ inpb,    // [256][9216] bf16    (immutable)
    unsigned short* __restrict__ inpT,    // [9216][256] bf16    (immutable)
    float* __restrict__ vTf,              // [160][256] f32      (sc1)
    float* __restrict__ vout,             // [256][10][16]
    u32* flags)                           // barrier flags (memset 0)
{
    const int blk  = blockIdx.x;
    const int tid  = threadIdx.x;
    const int lane = tid & 63;
    const int wid  = tid >> 6;
    unsigned ph = 0;

    __shared__ unsigned short Bl[16 * BLP];   // 18.7 KB (reused as prep transpose buf)
    __shared__ float c_loc[72];

    // ---------------- prep: inp -> bf16 [256][9216] and transpose [9216][256]
    if (blk < 45) stf(&blog[blk * 256 + tid], 0.f);
    for (int vb = blk; vb < 576; vb += GRID) {
        __syncthreads();                      // protect sh reuse across vb iters
        auto sh = (unsigned short (*)[65])Bl; // 64x65 shorts = 8.3 KB, fits in Bl
        const int kt = vb % 144;
        const int bt = vb / 144;
#pragma unroll
        for (int j = 0; j < 4; ++j) {
            int q     = j * 256 + tid;
            int b_loc = q >> 4;
            int kq    = (q & 15) * 4;
            float4 g = *(const float4*)&inp[(size_t)(bt * 64 + b_loc) * KTOT + kt * 64 + kq];
            unsigned short h0 = f2bf(g.x), h1 = f2bf(g.y), h2 = f2bf(g.z), h3 = f2bf(g.w);
            sh[kq][b_loc] = h0; sh[kq + 1][b_loc] = h1;
            sh[kq + 2][b_loc] = h2; sh[kq + 3][b_loc] = h3;
            u64 pk = (u64)h0 | ((u64)h1 << 16) | ((u64)h2 << 32) | ((u64)h3 << 48);
            st_u64((u64*)&inpb[(size_t)(bt * 64 + b_loc) * KTOT + kt * 64 + kq], pk);
        }
        __syncthreads();
#pragma unroll
        for (int j = 0; j < 4; ++j) {
            int q     = j * 256 + tid;
            int k_loc = q >> 4;
            int b4    = (q & 15) * 4;
            u64 pk = (u64)sh[k_loc][b4] | ((u64)sh[k_loc][b4 + 1] << 16)
                   | ((u64)sh[k_loc][b4 + 2] << 32) | ((u64)sh[k_loc][b4 + 3] << 48);
            st_u64((u64*)&inpT[(size_t)(kt * 64 + k_loc) * 256 + bt * 64 + b4], pk);
        }
    }
    gbar(flags, ++ph);

    for (int t = 0; t < 3; ++t) {
        // ---------------- spass: 640 virtual blocks over 512 real ----------
        for (int vb = blk; vb < 640; vb += GRID) {
            __syncthreads();                  // protect Bl/c_loc reuse across vb
            const int nt   = vb % 10;         // output capsule o
            const int ks   = (vb / 10) % 16;  // k-split
            const int mtg  = vb / 160;        // 0..3
            const int l15  = lane & 15;
            const int koff = (lane >> 4) * 8;
            const int k0   = ks * 576;
            const int i0   = ks * 72;
            const int mt   = mtg * 4 + wid;

            if (tid < 72) {
                const float* br = &blog[(size_t)(i0 + tid) * OC];
                float x[OC], m = -1e30f;
#pragma unroll
                for (int o = 0; o < OC; ++o) { x[o] = ldf(&br[o]); m = fmaxf(m, x[o]); }
                float ssum = 0.f;
#pragma unroll
                for (int o = 0; o < OC; ++o) ssum += expf(x[o] - m);
                c_loc[tid] = expf(x[nt] - m) / ssum;
            }
            __syncthreads();

#pragma unroll
            for (int jj = 0; jj < 5; ++jj) {
                int q = jj * 256 + tid;       // (i_loc, u) pairs: 72*16 = 1152
                if (q < 1152) {
                    int i_loc = q >> 4, u = q & 15;
                    const float* wr = W + (((size_t)(i0 + i_loc) * OC + nt) * OU + u) * IK;
                    float4 a = *(const float4*)wr;
                    float4 b = *(const float4*)(wr + 4);
                    float cc = c_loc[i_loc];
                    union { short8 v; unsigned short us[8]; } pk;
                    pk.us[0] = f2bf(cc * a.x); pk.us[1] = f2bf(cc * a.y);
                    pk.us[2] = f2bf(cc * a.z); pk.us[3] = f2bf(cc * a.w);
                    pk.us[4] = f2bf(cc * b.x); pk.us[5] = f2bf(cc * b.y);
                    pk.us[6] = f2bf(cc * b.z); pk.us[7] = f2bf(cc * b.w);
                    *(short8*)&Bl[u * BLP + i_loc * 8] = pk.v;
                }
            }
            __syncthreads();

            const unsigned short* ap  = inpb + (size_t)(mt * 16 + l15) * KTOT + k0 + koff;
            const unsigned short* bls = &Bl[l15 * BLP + koff];

            f32x4 acc = {0.f, 0.f, 0.f, 0.f};
#pragma unroll
            for (int kk = 0; kk < 18; ++kk) {
                short8 av = *(const short8*)(ap + kk * 32);   // plain: immutable
                short8 bv = *(const short8*)(bls + kk * 32);
                acc = __builtin_amdgcn_mfma_f32_16x16x32_bf16(av, bv, acc, 0, 0, 0);
            }

            float* pp = part + ((size_t)ks * NB + mt * 16 + (lane >> 4) * 4) * NTOT + nt * 16 + l15;
#pragma unroll
            for (int r = 0; r < 4; ++r)
                stf(&pp[(size_t)r * NTOT], acc[r]);
        }
        gbar(flags, ++ph);

        // ---------------- reduce partials + squash: 1 thread per element ---
        {
            int gtid = blk * 256 + tid;       // only blk < 160 active
            if (gtid < NB * NTOT) {
                float x[16];
#pragma unroll
                for (int ksr = 0; ksr < 16; ++ksr)
                    x[ksr] = ldf(&part[(size_t)ksr * (NB * NTOT) + gtid]);
                float s = 0.f;
#pragma unroll
                for (int ksr = 0; ksr < 16; ++ksr) s += x[ksr];
                float sq = s * s;
                sq += __shfl_xor(sq, 1);      // sum over u (aligned 16-lane groups)
                sq += __shfl_xor(sq, 2);
                sq += __shfl_xor(sq, 4);
                sq += __shfl_xor(sq, 8);
                float vv = s * (sq / ((1.f + sq) * sqrtf(sq + 1e-9f)));
                if (t == 2) {
                    vout[gtid] = vv;          // only final v is observable
                } else {
                    int n = gtid % NTOT, b = gtid / NTOT;
                    stf(&vTf[(size_t)n * 256 + b], vv);
                }
            }
        }

        if (t < 2) {
            gbar(flags, ++ph);
            // ---------------- delta: 2880 virtual waves over 2048 real -----
            for (int g = blk * 4 + wid; g < 2880; g += GRID * 4) {
                const int mt   = g % 576;
                const int ntp  = g / 576;     // 0..4 -> nt = ntp*2, ntp*2+1
                const int l15  = lane & 15;
                const int quad = lane >> 4;
                const int koff = quad * 8;
                const int nt0  = ntp * 2;

                const unsigned short* ap = inpT + (size_t)(mt * 16 + l15) * 256 + koff;
                const float* bp0 = vTf + (size_t)(nt0 * 16 + l15) * 256 + koff;
                const float* bp1 = bp0 + 16 * 256;

                f32x4 acc0 = {0.f, 0.f, 0.f, 0.f};
                f32x4 acc1 = {0.f, 0.f, 0.f, 0.f};
#pragma unroll
                for (int kk = 0; kk < 8; ++kk) {
                    short8 av = *(const short8*)(ap + kk * 32);  // plain: immutable
                    short8 b0 = ld_v8(bp0 + kk * 32);            // sc1 + cvt (bit-exact)
                    short8 b1 = ld_v8(bp1 + kk * 32);
                    acc0 = __builtin_amdgcn_mfma_f32_16x16x32_bf16(av, b0, acc0, 0, 0, 0);
                    acc1 = __builtin_amdgcn_mfma_f32_16x16x32_bf16(av, b1, acc1, 0, 0, 0);
                }

                // lane holds G[m=quad*4+r][n=l15]; m -> i_loc = quad>>1, k=(quad&1)*4+r
                const int i = mt * 2 + (quad >> 1);
                const float* wr0 = W + (((size_t)i * OC + nt0) * OU + l15) * IK + (quad & 1) * 4;
                float4 wf0 = *(const float4*)wr0;
                float4 wf1 = *(const float4*)(wr0 + OU * IK);   // nt0+1 adjacent in W
                float w0 = wf0.x * acc0[0] + wf0.y * acc0[1] + wf0.z * acc0[2] + wf0.w * acc0[3];
                float w1 = wf1.x * acc1[0] + wf1.y * acc1[1] + wf1.z * acc1[2] + wf1.w * acc1[3];

#pragma unroll
                for (int d = 0; d < 5; ++d) {
                    int m = (d == 0) ? 16 : (1 << (d - 1));   // 16, 1, 2, 4, 8
                    w0 += __shfl_xor(w0, m);
                    w1 += __shfl_xor(w1, m);
                }

                if ((lane & 31) == 0) {       // one writer per (i,o), no atomics
                    float* b0p = &blog[(size_t)i * OC + nt0];
                    stf(b0p,     ldf(b0p)     + w0 * (1.0f / NB));
                    stf(b0p + 1, ldf(b0p + 1) + w1 * (1.0f / NB));
                }
            }
            gbar(flags, ++ph);
        }
    }
}

// ===================== fallback: proven multi-kernel path (127.9us) =====

__global__ __launch_bounds__(256) void prep_kernel(
    const float* __restrict__ inp,
    float* __restrict__ blog,
    unsigned short* __restrict__ inpb,
    unsigned short* __restrict__ inpT)
{
    const int kt  = blockIdx.x;
    const int bt  = blockIdx.y;
    const int tid = threadIdx.x;
    {
        int bid = blockIdx.y * 144 + blockIdx.x;
        if (bid < 45) blog[bid * 256 + tid] = 0.f;
    }
    __shared__ unsigned short sh[64][65];
#pragma unroll
    for (int j = 0; j < 4; ++j) {
        int q = j * 256 + tid;
        int b_loc = q >> 4;
        int kq = (q & 15) * 4;
        float4 g = *(const float4*)&inp[(size_t)(bt * 64 + b_loc) * KTOT + kt * 64 + kq];
        unsigned short h0 = f2bf(g.x), h1 = f2bf(g.y), h2 = f2bf(g.z), h3 = f2bf(g.w);
        sh[kq][b_loc] = h0; sh[kq + 1][b_loc] = h1;
        sh[kq + 2][b_loc] = h2; sh[kq + 3][b_loc] = h3;
        short4 pk = { (short)h0, (short)h1, (short)h2, (short)h3 };
        *(short4*)&inpb[(size_t)(bt * 64 + b_loc) * KTOT + kt * 64 + kq] = pk;
    }
    __syncthreads();
#pragma unroll
    for (int j = 0; j < 4; ++j) {
        int q = j * 256 + tid;
        int k_loc = q >> 4;
        int b4 = (q & 15) * 4;
        short4 pk = { (short)sh[k_loc][b4],     (short)sh[k_loc][b4 + 1],
                      (short)sh[k_loc][b4 + 2], (short)sh[k_loc][b4 + 3] };
        *(short4*)&inpT[(size_t)(kt * 64 + k_loc) * 256 + bt * 64 + b4] = pk;
    }
}

__global__ __launch_bounds__(256) void spass_kernel(
    const unsigned short* __restrict__ inpb,
    const float* __restrict__ W,
    const float* __restrict__ blog,
    float* __restrict__ part)
{
    const int bid  = blockIdx.x;
    const int nt   = bid % 10;
    const int ks   = (bid / 10) % 16;
    const int mtg  = bid / 160;
    const int tid  = threadIdx.x;
    const int w    = tid >> 6;
    const int lane = tid & 63;
    const int l15  = lane & 15;
    const int koff = (lane >> 4) * 8;
    const int k0   = ks * 576;
    const int i0   = ks * 72;
    const int mt   = mtg * 4 + w;

    __shared__ unsigned short Bl[16 * BLP];
    __shared__ float c_loc[72];

    if (tid < 72) {
        const float* br = &blog[(size_t)(i0 + tid) * OC];
        float x[OC], m = -1e30f;
#pragma unroll
        for (int o = 0; o < OC; ++o) { x[o] = br[o]; m = fmaxf(m, x[o]); }
        float ssum = 0.f;
#pragma unroll
        for (int o = 0; o < OC; ++o) ssum += expf(x[o] - m);
        c_loc[tid] = expf(x[nt] - m) / ssum;
    }
    __syncthreads();
#pragma unroll
    for (int jj = 0; jj < 5; ++jj) {
        int q = jj * 256 + tid;
        if (q < 1152) {
            int i_loc = q >> 4, u = q & 15;
            const float* wr = W + (((size_t)(i0 + i_loc) * OC + nt) * OU + u) * IK;
            float4 a = *(const float4*)wr;
            float4 b = *(const float4*)(wr + 4);
            float cc = c_loc[i_loc];
            union { short8 v; unsigned short us[8]; } pk;
            pk.us[0] = f2bf(cc * a.x); pk.us[1] = f2bf(cc * a.y);
            pk.us[2] = f2bf(cc * a.z); pk.us[3] = f2bf(cc * a.w);
            pk.us[4] = f2bf(cc * b.x); pk.us[5] = f2bf(cc * b.y);
            pk.us[6] = f2bf(cc * b.z); pk.us[7] = f2bf(cc * b.w);
            *(short8*)&Bl[u * BLP + i_loc * 8] = pk.v;
        }
    }
    __syncthreads();

    const unsigned short* ap  = inpb + (size_t)(mt * 16 + l15) * KTOT + k0 + koff;
    const unsigned short* bls = &Bl[l15 * BLP + koff];
    f32x4 acc = {0.f, 0.f, 0.f, 0.f};
#pragma unroll
    for (int kk = 0; kk < 18; ++kk) {
        short8 av = *(const short8*)(ap + kk * 32);
        short8 bv = *(const short8*)(bls + kk * 32);
        acc = __builtin_amdgcn_mfma_f32_16x16x32_bf16(av, bv, acc, 0, 0, 0);
    }
    float* pp = part + ((size_t)ks * NB + mt * 16 + (lane >> 4) * 4) * NTOT + nt * 16 + l15;
#pragma unroll
    for (int r = 0; r < 4; ++r)
        pp[(size_t)r * NTOT] = acc[r];
}

__global__ __launch_bounds__(256) void reduce_squash_kernel(
    const float* __restrict__ part, float* __restrict__ vout,
    unsigned short* __restrict__ vT)
{
    const int tid = threadIdx.x;
    const int el  = tid & 31;
    const int kl  = tid >> 5;
    const int e   = blockIdx.x * 32 + el;

    float a = part[(size_t)(kl * 2) * (NB * NTOT) + e]
            + part[(size_t)(kl * 2 + 1) * (NB * NTOT) + e];

    __shared__ float red[8][36];
    red[kl][el] = a;
    __syncthreads();

    if (tid < 32) {
        float s = ((red[0][el] + red[1][el]) + (red[2][el] + red[3][el]))
                + ((red[4][el] + red[5][el]) + (red[6][el] + red[7][el]));
        float sq = s * s;
        sq += __shfl_xor(sq, 1);
        sq += __shfl_xor(sq, 2);
        sq += __shfl_xor(sq, 4);
        sq += __shfl_xor(sq, 8);
        float vv = s * (sq / ((1.f + sq) * sqrtf(sq + 1e-9f)));
        vout[e] = vv;
        int n = e % NTOT, b = e / NTOT;
        vT[(size_t)n * 256 + b] = f2bf(vv);
    }
}

__global__ __launch_bounds__(256) void delta_kernel(
    const unsigned short* __restrict__ inpT,
    const unsigned short* __restrict__ vT,
    const float* __restrict__ W,
    float* __restrict__ blog)
{
    const int g    = blockIdx.x * 4 + (threadIdx.x >> 6);
    const int lane = threadIdx.x & 63;
    const int mt   = g % 576;
    const int ntp  = g / 576;
    const int l15  = lane & 15;
    const int quad = lane >> 4;
    const int koff = quad * 8;
    const int nt0  = ntp * 2;

    const unsigned short* ap  = inpT + (size_t)(mt * 16 + l15) * 256 + koff;
    const unsigned short* bp0 = vT   + (size_t)(nt0 * 16 + l15) * 256 + koff;
    const unsigned short* bp1 = bp0 + 16 * 256;

    f32x4 acc0 = {0.f, 0.f, 0.f, 0.f};
    f32x4 acc1 = {0.f, 0.f, 0.f, 0.f};
#pragma unroll
    for (int kk = 0; kk < 8; ++kk) {
        short8 av = *(const short8*)(ap  + kk * 32);
        short8 b0 = *(const short8*)(bp0 + kk * 32);
        short8 b1 = *(const short8*)(bp1 + kk * 32);
        acc0 = __builtin_amdgcn_mfma_f32_16x16x32_bf16(av, b0, acc0, 0, 0, 0);
        acc1 = __builtin_amdgcn_mfma_f32_16x16x32_bf16(av, b1, acc1, 0, 0, 0);
    }
    const int i = mt * 2 + (quad >> 1);
    const float* wr0 = W + (((size_t)i * OC + nt0) * OU + l15) * IK + (quad & 1) * 4;
    float4 wf0 = *(const float4*)wr0;
    float4 wf1 = *(const float4*)(wr0 + OU * IK);
    float w0 = wf0.x * acc0[0] + wf0.y * acc0[1] + wf0.z * acc0[2] + wf0.w * acc0[3];
    float w1 = wf1.x * acc1[0] + wf1.y * acc1[1] + wf1.z * acc1[2] + wf1.w * acc1[3];
#pragma unroll
    for (int d = 0; d < 5; ++d) {
        int m = (d == 0) ? 16 : (1 << (d - 1));
        w0 += __shfl_xor(w0, m);
        w1 += __shfl_xor(w1, m);
    }
    if ((lane & 31) == 0) {
        blog[(size_t)i * OC + nt0]     += w0 * (1.0f / NB);
        blog[(size_t)i * OC + nt0 + 1] += w1 * (1.0f / NB);
    }
}

extern "C" void kernel_launch(void* const* d_in, const int* in_sizes, int n_in,
                              void* d_out, int out_size, void* d_ws, size_t ws_size,
                              hipStream_t stream) {
    const float* inp = (const float*)d_in[0];   // [256][1152][8]
    const float* W   = (const float*)d_in[1];   // [1152][10][16][8]
    float* vout = (float*)d_out;                // [256][10][16]

    float* blog = (float*)d_ws;                              // 11,520 f
    float* part = blog + IC * OC;                            // 655,360 f
    unsigned short* inpb = (unsigned short*)(part + (size_t)S_KS * NB * NTOT);
    unsigned short* inpT = inpb + (size_t)NB * KTOT;         // 2,359,296 u16
    float* vTf = (float*)(inpT + (size_t)KTOT * 256);        // 40,960 f32
    size_t bar_off = (((size_t)(vTf + NTOT * 256) - (size_t)d_ws) + 127) & ~(size_t)127;
    u32* flags = (u32*)((char*)d_ws + bar_off);              // 512 flags + rel word

    hipMemsetAsync(flags, 0, 4096, stream);     // reset barrier state each replay

    void* args[] = { (void*)&inp, (void*)&W, (void*)&blog, (void*)&part,
                     (void*)&inpb, (void*)&inpT, (void*)&vTf, (void*)&vout,
                     (void*)&flags };
    hipError_t err = hipLaunchCooperativeKernel(fused_kernel, dim3(GRID), dim3(256),
                                                args, 0u, stream);
    if (err != hipSuccess) {
        // graceful fallback: the verified multi-kernel path
        unsigned short* vT = (unsigned short*)vTf;   // reuse region as bf16 vT
        prep_kernel<<<dim3(144, 4), dim3(256), 0, stream>>>(inp, blog, inpb, inpT);
        for (int t = 0; t < 3; ++t) {
            spass_kernel<<<dim3(640), dim3(256), 0, stream>>>(inpb, W, blog, part);
            reduce_squash_kernel<<<dim3(NB * NTOT / 32), dim3(256), 0, stream>>>(part, vout, vT);
            if (t < 2)
                delta_kernel<<<dim3(720), dim3(256), 0, stream>>>(inpT, vT, W, blog);
        }
    }
}

// Round 7
// 130.133 us; speedup vs baseline: 1.9479x; 1.7510x over previous
//
#include <hip/hip_runtime.h>
#include <math.h>

#define NB 256     // batch
#define IC 1152    // input capsules
#define OC 10      // output capsules
#define OU 16      // output units
#define IK 8       // input units
#define KTOT (IC * IK)        // 9216
#define NTOT (OC * OU)        // 160
#define S_KS 16               // s-pass K-splits (576 k = 18 MFMA each)
#define BLP 584               // B-tile row pitch in shorts (576 + 8 pad)

typedef __attribute__((ext_vector_type(8))) short short8;
typedef __attribute__((ext_vector_type(4))) float f32x4;

static __device__ __forceinline__ unsigned short f2bf(float f) {
    unsigned u = __float_as_uint(f);
    unsigned r = (u + 0x7FFF + ((u >> 16) & 1)) >> 16;   // RNE
    return (unsigned short)r;
}

// ===== K1: [spass0 || prep] fused as independent block ranges. =====
// t=0: softmax(0) == 1.0f/10.0f == 0.1f literal (bit-exact), so spass0
// needs no blog and reads f32 inp directly (inline f2bf == reading inpb,
// bit-identical). Blocks 0..639: spass0. Blocks 640..1215: prep (inp ->
// bf16 inpb [256][9216] + bf16 transpose inpT [9216][256] + blog zero).
// This removes one kernel boundary AND hides prep (~4-5us) under spass0.
__global__ __launch_bounds__(256) void k1_spass0_prep(
    const float* __restrict__ inp,            // [256][1152][8]
    const float* __restrict__ W,              // [1152][10][16][8]
    float* __restrict__ blog,                 // [1152][10]
    float* __restrict__ part,                 // [16][256][160]
    unsigned short* __restrict__ inpb,        // [256][9216]
    unsigned short* __restrict__ inpT)        // [9216][256]
{
    const int blk = blockIdx.x;
    const int tid = threadIdx.x;

    __shared__ unsigned short Bl[16 * BLP];   // 18.7 KB; prep reuses as 64x65

    if (blk < 640) {
        // ---------------- spass0 (c = 0.1 exactly, A from f32 inp) --------
        const int nt   = blk % 10;
        const int ks   = (blk / 10) % 16;
        const int mtg  = blk / 160;
        const int w    = tid >> 6;
        const int lane = tid & 63;
        const int l15  = lane & 15;
        const int koff = (lane >> 4) * 8;
        const int k0   = ks * 576;
        const int i0   = ks * 72;
        const int mt   = mtg * 4 + w;

#pragma unroll
        for (int jj = 0; jj < 5; ++jj) {
            int q = jj * 256 + tid;           // (i_loc, u) pairs: 72*16 = 1152
            if (q < 1152) {
                int i_loc = q >> 4, u = q & 15;
                const float* wr = W + (((size_t)(i0 + i_loc) * OC + nt) * OU + u) * IK;
                float4 a = *(const float4*)wr;
                float4 b = *(const float4*)(wr + 4);
                const float cc = 0.1f;        // == softmax(0) in f32, bit-exact
                union { short8 v; unsigned short us[8]; } pk;
                pk.us[0] = f2bf(cc * a.x); pk.us[1] = f2bf(cc * a.y);
                pk.us[2] = f2bf(cc * a.z); pk.us[3] = f2bf(cc * a.w);
                pk.us[4] = f2bf(cc * b.x); pk.us[5] = f2bf(cc * b.y);
                pk.us[6] = f2bf(cc * b.z); pk.us[7] = f2bf(cc * b.w);
                *(short8*)&Bl[u * BLP + i_loc * 8] = pk.v;
            }
        }
        __syncthreads();

        const float* af = inp + (size_t)(mt * 16 + l15) * KTOT + k0 + koff;
        const unsigned short* bls = &Bl[l15 * BLP + koff];

        f32x4 acc = {0.f, 0.f, 0.f, 0.f};
#pragma unroll
        for (int kk = 0; kk < 18; ++kk) {
            float4 a0 = *(const float4*)(af + kk * 32);
            float4 a1 = *(const float4*)(af + kk * 32 + 4);
            union { short8 v; unsigned short us[8]; } A;
            A.us[0] = f2bf(a0.x); A.us[1] = f2bf(a0.y);
            A.us[2] = f2bf(a0.z); A.us[3] = f2bf(a0.w);
            A.us[4] = f2bf(a1.x); A.us[5] = f2bf(a1.y);
            A.us[6] = f2bf(a1.z); A.us[7] = f2bf(a1.w);
            short8 bv = *(const short8*)(bls + kk * 32);
            acc = __builtin_amdgcn_mfma_f32_16x16x32_bf16(A.v, bv, acc, 0, 0, 0);
        }

        float* pp = part + ((size_t)ks * NB + mt * 16 + (lane >> 4) * 4) * NTOT + nt * 16 + l15;
#pragma unroll
        for (int r = 0; r < 4; ++r)
            pp[(size_t)r * NTOT] = acc[r];
    } else {
        // ---------------- prep (verbatim R0 body, one tile per block) -----
        const int vb = blk - 640;             // 0..575
        const int kt = vb % 144;
        const int bt = vb / 144;
        if (vb < 45) blog[vb * 256 + tid] = 0.f;

        auto sh = (unsigned short (*)[65])Bl; // 64x65 shorts = 8.3 KB
#pragma unroll
        for (int j = 0; j < 4; ++j) {
            int q     = j * 256 + tid;
            int b_loc = q >> 4;
            int kq    = (q & 15) * 4;
            float4 g = *(const float4*)&inp[(size_t)(bt * 64 + b_loc) * KTOT + kt * 64 + kq];
            unsigned short h0 = f2bf(g.x), h1 = f2bf(g.y), h2 = f2bf(g.z), h3 = f2bf(g.w);
            sh[kq][b_loc] = h0; sh[kq + 1][b_loc] = h1;
            sh[kq + 2][b_loc] = h2; sh[kq + 3][b_loc] = h3;
            short4 pk = { (short)h0, (short)h1, (short)h2, (short)h3 };
            *(short4*)&inpb[(size_t)(bt * 64 + b_loc) * KTOT + kt * 64 + kq] = pk;
        }
        __syncthreads();
#pragma unroll
        for (int j = 0; j < 4; ++j) {
            int q     = j * 256 + tid;
            int k_loc = q >> 4;
            int b4    = (q & 15) * 4;
            short4 pk = { (short)sh[k_loc][b4],     (short)sh[k_loc][b4 + 1],
                          (short)sh[k_loc][b4 + 2], (short)sh[k_loc][b4 + 3] };
            *(short4*)&inpT[(size_t)(kt * 64 + k_loc) * 256 + bt * 64 + b4] = pk;
        }
    }
}

// ===== spass (t>=1): verbatim R0 (softmax + c*W staging + MFMA) =====
__global__ __launch_bounds__(256) void spass_kernel(
    const unsigned short* __restrict__ inpb,
    const float* __restrict__ W,
    const float* __restrict__ blog,
    float* __restrict__ part)
{
    const int bid  = blockIdx.x;
    const int nt   = bid % 10;
    const int ks   = (bid / 10) % 16;
    const int mtg  = bid / 160;
    const int tid  = threadIdx.x;
    const int w    = tid >> 6;
    const int lane = tid & 63;
    const int l15  = lane & 15;
    const int koff = (lane >> 4) * 8;
    const int k0   = ks * 576;
    const int i0   = ks * 72;
    const int mt   = mtg * 4 + w;

    __shared__ unsigned short Bl[16 * BLP];
    __shared__ float c_loc[72];

    if (tid < 72) {
        const float* br = &blog[(size_t)(i0 + tid) * OC];
        float x[OC], m = -1e30f;
#pragma unroll
        for (int o = 0; o < OC; ++o) { x[o] = br[o]; m = fmaxf(m, x[o]); }
        float ssum = 0.f;
#pragma unroll
        for (int o = 0; o < OC; ++o) ssum += expf(x[o] - m);
        c_loc[tid] = expf(x[nt] - m) / ssum;
    }
    __syncthreads();
#pragma unroll
    for (int jj = 0; jj < 5; ++jj) {
        int q = jj * 256 + tid;
        if (q < 1152) {
            int i_loc = q >> 4, u = q & 15;
            const float* wr = W + (((size_t)(i0 + i_loc) * OC + nt) * OU + u) * IK;
            float4 a = *(const float4*)wr;
            float4 b = *(const float4*)(wr + 4);
            float cc = c_loc[i_loc];
            union { short8 v; unsigned short us[8]; } pk;
            pk.us[0] = f2bf(cc * a.x); pk.us[1] = f2bf(cc * a.y);
            pk.us[2] = f2bf(cc * a.z); pk.us[3] = f2bf(cc * a.w);
            pk.us[4] = f2bf(cc * b.x); pk.us[5] = f2bf(cc * b.y);
            pk.us[6] = f2bf(cc * b.z); pk.us[7] = f2bf(cc * b.w);
            *(short8*)&Bl[u * BLP + i_loc * 8] = pk.v;
        }
    }
    __syncthreads();

    const unsigned short* ap  = inpb + (size_t)(mt * 16 + l15) * KTOT + k0 + koff;
    const unsigned short* bls = &Bl[l15 * BLP + koff];
    f32x4 acc = {0.f, 0.f, 0.f, 0.f};
#pragma unroll
    for (int kk = 0; kk < 18; ++kk) {
        short8 av = *(const short8*)(ap + kk * 32);
        short8 bv = *(const short8*)(bls + kk * 32);
        acc = __builtin_amdgcn_mfma_f32_16x16x32_bf16(av, bv, acc, 0, 0, 0);
    }
    float* pp = part + ((size_t)ks * NB + mt * 16 + (lane >> 4) * 4) * NTOT + nt * 16 + l15;
#pragma unroll
    for (int r = 0; r < 4; ++r)
        pp[(size_t)r * NTOT] = acc[r];
}

// ===== reduce+squash: 160 blocks, 1 thread per output (was 1280 blocks
// with 87.5% idle lanes). 16-way part sum + aligned 16-lane shuffle squash
// (body proven in the R4/R6 fused kernel). =====
__global__ __launch_bounds__(256) void reduce_squash_kernel(
    const float* __restrict__ part, float* __restrict__ vout,
    unsigned short* __restrict__ vT)
{
    const int gtid = blockIdx.x * 256 + threadIdx.x;   // 160*256 = 40960
    float s = 0.f;
#pragma unroll
    for (int ks = 0; ks < 16; ++ks)
        s += part[(size_t)ks * (NB * NTOT) + gtid];
    float sq = s * s;
    sq += __shfl_xor(sq, 1);     // sum over u (aligned 16-lane groups)
    sq += __shfl_xor(sq, 2);
    sq += __shfl_xor(sq, 4);
    sq += __shfl_xor(sq, 8);
    float vv = s * (sq / ((1.f + sq) * sqrtf(sq + 1e-9f)));
    vout[gtid] = vv;
    int n = gtid % NTOT, b = gtid / NTOT;
    vT[(size_t)n * 256 + b] = f2bf(vv);
}

// ===== delta: verbatim R0 (G = inpT*vT via MFMA, dot with W, += blog) ===
__global__ __launch_bounds__(256) void delta_kernel(
    const unsigned short* __restrict__ inpT,
    const unsigned short* __restrict__ vT,
    const float* __restrict__ W,
    float* __restrict__ blog)
{
    const int g    = blockIdx.x * 4 + (threadIdx.x >> 6);
    const int lane = threadIdx.x & 63;
    const int mt   = g % 576;
    const int ntp  = g / 576;
    const int l15  = lane & 15;
    const int quad = lane >> 4;
    const int koff = quad * 8;
    const int nt0  = ntp * 2;

    const unsigned short* ap  = inpT + (size_t)(mt * 16 + l15) * 256 + koff;
    const unsigned short* bp0 = vT   + (size_t)(nt0 * 16 + l15) * 256 + koff;
    const unsigned short* bp1 = bp0 + 16 * 256;

    f32x4 acc0 = {0.f, 0.f, 0.f, 0.f};
    f32x4 acc1 = {0.f, 0.f, 0.f, 0.f};
#pragma unroll
    for (int kk = 0; kk < 8; ++kk) {
        short8 av = *(const short8*)(ap  + kk * 32);
        short8 b0 = *(const short8*)(bp0 + kk * 32);
        short8 b1 = *(const short8*)(bp1 + kk * 32);
        acc0 = __builtin_amdgcn_mfma_f32_16x16x32_bf16(av, b0, acc0, 0, 0, 0);
        acc1 = __builtin_amdgcn_mfma_f32_16x16x32_bf16(av, b1, acc1, 0, 0, 0);
    }
    const int i = mt * 2 + (quad >> 1);
    const float* wr0 = W + (((size_t)i * OC + nt0) * OU + l15) * IK + (quad & 1) * 4;
    float4 wf0 = *(const float4*)wr0;
    float4 wf1 = *(const float4*)(wr0 + OU * IK);
    float w0 = wf0.x * acc0[0] + wf0.y * acc0[1] + wf0.z * acc0[2] + wf0.w * acc0[3];
    float w1 = wf1.x * acc1[0] + wf1.y * acc1[1] + wf1.z * acc1[2] + wf1.w * acc1[3];
#pragma unroll
    for (int d = 0; d < 5; ++d) {
        int m = (d == 0) ? 16 : (1 << (d - 1));
        w0 += __shfl_xor(w0, m);
        w1 += __shfl_xor(w1, m);
    }
    if ((lane & 31) == 0) {
        blog[(size_t)i * OC + nt0]     += w0 * (1.0f / NB);
        blog[(size_t)i * OC + nt0 + 1] += w1 * (1.0f / NB);
    }
}

extern "C" void kernel_launch(void* const* d_in, const int* in_sizes, int n_in,
                              void* d_out, int out_size, void* d_ws, size_t ws_size,
                              hipStream_t stream) {
    const float* inp = (const float*)d_in[0];   // [256][1152][8]
    const float* W   = (const float*)d_in[1];   // [1152][10][16][8]
    float* vout = (float*)d_out;                // [256][10][16]

    float* blog = (float*)d_ws;                              // 11,520 f
    float* part = blog + IC * OC;                            // 655,360 f
    unsigned short* inpb = (unsigned short*)(part + (size_t)S_KS * NB * NTOT);
    unsigned short* inpT = inpb + (size_t)NB * KTOT;         // 2,359,296 u16
    unsigned short* vT   = inpT + (size_t)KTOT * 256;        // 40,960 u16

    // 8 launches (was 9): prep hidden under spass0 in K1.
    k1_spass0_prep<<<dim3(1216), dim3(256), 0, stream>>>(inp, W, blog, part, inpb, inpT);
    reduce_squash_kernel<<<dim3(160), dim3(256), 0, stream>>>(part, vout, vT);   // t=0
    delta_kernel<<<dim3(720), dim3(256), 0, stream>>>(inpT, vT, W, blog);
    spass_kernel<<<dim3(640), dim3(256), 0, stream>>>(inpb, W, blog, part);      // t=1
    reduce_squash_kernel<<<dim3(160), dim3(256), 0, stream>>>(part, vout, vT);
    delta_kernel<<<dim3(720), dim3(256), 0, stream>>>(inpT, vT, W, blog);
    spass_kernel<<<dim3(640), dim3(256), 0, stream>>>(inpb, W, blog, part);      // t=2
    reduce_squash_kernel<<<dim3(160), dim3(256), 0, stream>>>(part, vout, vT);
}